// Round 6
// baseline (144.622 us; speedup 1.0000x reference)
//
#include <hip/hip_runtime.h>
#include <hip/hip_bf16.h>
#include <string.h>

#define N 4096
#define D 512
#define NB 32            // N/128 tile-rows; triangle blocks = NB*(NB+1)/2 = 528
#define NBLK (NB*(NB+1)/2)
#define MARGIN 0.5f
#define FINF __builtin_huge_valf()
#define UINF 0x7F800000u

typedef __attribute__((ext_vector_type(8))) short bf16x8;   // 8 bf16 (4 VGPRs)
typedef __attribute__((ext_vector_type(4))) float f32x4;

__device__ inline float wave_sum(float v){
  #pragma unroll
  for (int off=32; off>0; off>>=1) v += __shfl_down(v, off, 64);
  return v;
}

// Pass 0: X (f32) -> bf16, row squared norms, init atomic arrays + ticket counter.
__global__ __launch_bounds__(128) void prep_kernel(const float* __restrict__ X,
    __hip_bfloat16* __restrict__ Xb, float* __restrict__ sq,
    unsigned int* __restrict__ hp2u, unsigned int* __restrict__ nm2u,
    unsigned int* __restrict__ counter){
  const int row = blockIdx.x;
  const int t = threadIdx.x;
  const float4 v = *(const float4*)(X + (size_t)row*D + t*4);
  ushort4 s;
  __hip_bfloat16 h;
  h = __float2bfloat16(v.x); memcpy(&s.x, &h, 2);
  h = __float2bfloat16(v.y); memcpy(&s.y, &h, 2);
  h = __float2bfloat16(v.z); memcpy(&s.z, &h, 2);
  h = __float2bfloat16(v.w); memcpy(&s.w, &h, 2);
  *(ushort4*)((unsigned short*)Xb + (size_t)row*D + t*4) = s;
  float ss = v.x*v.x + v.y*v.y + v.z*v.z + v.w*v.w;
  ss = wave_sum(ss);
  __shared__ float red[2];
  if ((t & 63) == 0) red[t >> 6] = ss;
  __syncthreads();
  if (t == 0){
    sq[row] = red[0] + red[1];
    hp2u[row] = 0u;                 // max-accumulator (d^2 domain, >= 0)
    nm2u[row] = UINF;               // +inf: min-accumulator
    if (row == 0) counter[0] = 0u;
  }
}

// Fused triangle GEMM + hardest-pos/neg reductions + last-block final reduce.
// NO LDS staging, NO K-loop barriers: MFMA fragments are loaded directly
// global->VGPR (16B/lane, K-offset folds into the load immediate). The 4 MB
// Xb panel is L1/L2-resident; the compiler pipelines loads across the fully
// unrolled K-loop with fine-grained vmcnt waits instead of barrier drains.
__global__ __launch_bounds__(256,2) void gemm_fused(const __hip_bfloat16* __restrict__ Xb,
    const float* __restrict__ sq, const int* __restrict__ lab,
    unsigned int* __restrict__ hp2u, unsigned int* __restrict__ nm2u,
    unsigned int* __restrict__ counter, float* __restrict__ out){
  __shared__ float sqi[128];
  __shared__ float sqj[128];
  __shared__ int labi_s[128];
  __shared__ int labj_s[128];
  __shared__ unsigned int hpl[128], nml[128];   // per-block row combine
  __shared__ unsigned int hpc[128], nmc[128];   // per-block col combine
  __shared__ unsigned int tick;

  // linear block -> (bi, bj) with bi <= bj
  int rem = blockIdx.x, bi = 0;
  while (rem >= NB - bi){ rem -= NB - bi; bi++; }
  const int bj = bi + rem;
  const int row0 = bi * 128, col0 = bj * 128;

  const int tid = threadIdx.x;
  const int wave = tid >> 6, lane = tid & 63;
  const int wr = (wave >> 1) * 64, wc = (wave & 1) * 64;
  const int fr = lane & 15, q = lane >> 4;

  if (tid < 128) {
    sqi[tid] = sq[row0 + tid]; sqj[tid] = sq[col0 + tid];
    labi_s[tid] = lab[row0 + tid]; labj_s[tid] = lab[col0 + tid];
    hpl[tid] = 0u; nml[tid] = UINF; hpc[tid] = 0u; nmc[tid] = UINF;
  }

  // Per-lane fragment base pointers: A-operand layout A[m=lane&15][k=q*8+j].
  const __hip_bfloat16* pa[4];
  const __hip_bfloat16* pb[4];
  #pragma unroll
  for (int a=0;a<4;a++){
    pa[a] = Xb + (size_t)(row0 + wr + a*16 + fr)*D + q*8;
    pb[a] = Xb + (size_t)(col0 + wc + a*16 + fr)*D + q*8;
  }

  f32x4 acc[4][4];
  #pragma unroll
  for (int a=0;a<4;a++)
    #pragma unroll
    for (int b=0;b<4;b++)
      acc[a][b] = (f32x4){0.f,0.f,0.f,0.f};

  // Barrier-free K-loop: 16 steps x (8 dwordx4 loads + 16 MFMA), fully unrolled.
  #pragma unroll
  for (int it = 0; it < D/32; ++it){
    bf16x8 af[4], bfr[4];
    #pragma unroll
    for (int a=0;a<4;a++){
      af[a]  = *(const bf16x8*)(pa[a] + it*32);   // byte offset 64*it -> imm
      bfr[a] = *(const bf16x8*)(pb[a] + it*32);
    }
    #pragma unroll
    for (int a=0;a<4;a++)
      #pragma unroll
      for (int b=0;b<4;b++)
        acc[a][b] = __builtin_amdgcn_mfma_f32_16x16x32_bf16(af[a], bfr[b], acc[a][b], 0, 0, 0);
  }

  __syncthreads();   // sqi/labi/LDS-combine-array init visible to all waves

  // Epilogue. C/D layout: col=lane&15, row=(lane>>4)*4+v (m89-verified).
  const int colq = lane & 15, g4 = lane >> 4, rowq = g4 * 4;
  int   labi_r[16]; float sqi_r[16];
  #pragma unroll
  for (int a=0;a<4;a++)
    #pragma unroll
    for (int v=0;v<4;v++){
      const int iloc = wr + a*16 + rowq + v;
      labi_r[a*4+v] = labi_s[iloc];
      sqi_r[a*4+v]  = sqi[iloc];
    }

  float pmax_r[16], nmin_r[16];
  #pragma unroll
  for (int k=0;k<16;k++){ pmax_r[k] = 0.f; nmin_r[k] = FINF; }
  float cpos[4], cmin[4];

  #pragma unroll
  for (int b=0;b<4;b++){
    const int jloc = wc + b*16 + colq;
    const float sj = sqj[jloc];
    const int lj = labj_s[jloc];
    float cp = 0.f, cn = FINF;
    #pragma unroll
    for (int a=0;a<4;a++)
      #pragma unroll
      for (int v=0;v<4;v++){
        const int k = a*4+v;
        const float d2 = fmaf(acc[a][b][v], -2.0f, sqi_r[k] + sj);
        const bool same = (labi_r[k] == lj);         // covers diag (i==j)
        const float sp = same ? d2 : 0.0f;           // positive candidate
        const float sn = same ? FINF : d2;           // negative candidate
        pmax_r[k] = fmaxf(pmax_r[k], sp);
        nmin_r[k] = fminf(nmin_r[k], sn);
        cp = fmaxf(cp, sp);
        cn = fminf(cn, sn);
      }
    cpos[b] = cp; cmin[b] = cn;
  }

  // Row-direction: xor-reduce across the 16 lanes sharing a row -> LDS atomic.
  #pragma unroll
  for (int k=0;k<16;k++){
    float p = pmax_r[k], n = nmin_r[k];
    #pragma unroll
    for (int m=1;m<16;m<<=1){
      p = fmaxf(p, __shfl_xor(p, m, 64));
      n = fminf(n, __shfl_xor(n, m, 64));
    }
    if (colq == 0){
      const int il = wr + (k>>2)*16 + rowq + (k&3);
      atomicMax(&hpl[il], __float_as_uint(p));                 // p >= 0
      atomicMin(&nml[il], __float_as_uint(fmaxf(n, 0.f)));     // clamp: monotone
    }
  }
  // Column-direction (symmetry): xor-reduce across the 4 lane-groups -> LDS atomic.
  #pragma unroll
  for (int b=0;b<4;b++){
    float p = cpos[b], n = cmin[b];
    p = fmaxf(p, __shfl_xor(p, 16, 64)); p = fmaxf(p, __shfl_xor(p, 32, 64));
    n = fminf(n, __shfl_xor(n, 16, 64)); n = fminf(n, __shfl_xor(n, 32, 64));
    if (g4 == 0){
      const int jl = wc + b*16 + colq;
      atomicMax(&hpc[jl], __float_as_uint(p));
      atomicMin(&nmc[jl], __float_as_uint(fmaxf(n, 0.f)));
    }
  }

  __syncthreads();
  // One global flush: threads 0-127 do rows, 128-255 do cols (2 atomics each).
  if (tid < 128){
    atomicMax(hp2u + row0 + tid, hpl[tid]);
    atomicMin(nm2u + row0 + tid, nml[tid]);
  } else {
    const int t2 = tid - 128;
    atomicMax(hp2u + col0 + t2, hpc[t2]);
    atomicMin(nm2u + col0 + t2, nmc[t2]);
  }

  // Last-block final reduction (ticket).
  __threadfence();
  __syncthreads();
  if (tid == 0) tick = atomicAdd(counter, 1u);
  __syncthreads();
  if (tick == NBLK - 1){
    float s = 0.f;
    #pragma unroll
    for (int itr = 0; itr < 16; ++itr){
      const int i = tid + itr * 256;
      // non-destructive device-scope atomic reads (max(x,0)=x for our domains)
      const float hp2 = __uint_as_float(atomicMax(hp2u + i, 0u));
      const float nm2 = __uint_as_float(atomicMax(nm2u + i, 0u));
      s += sqrtf(hp2 + 1e-12f) + fmaxf(MARGIN - sqrtf(nm2 + 1e-12f), 0.f);
    }
    s = wave_sum(s);
    if ((tid & 63) == 0) sqi[tid >> 6] = s;   // reuse LDS as scratch
    __syncthreads();
    if (tid == 0) out[0] = (sqi[0] + sqi[1] + sqi[2] + sqi[3]) * (1.0f / (float)N);
  }
}

extern "C" void kernel_launch(void* const* d_in, const int* in_sizes, int n_in,
                              void* d_out, int out_size, void* d_ws, size_t ws_size,
                              hipStream_t stream) {
  (void)in_sizes; (void)n_in; (void)out_size; (void)ws_size;
  const float* X  = (const float*)d_in[0];
  const int* lab  = (const int*)d_in[1];
  float* out      = (float*)d_out;

  char* ws = (char*)d_ws;
  __hip_bfloat16* Xb    = (__hip_bfloat16*)ws;                 // 4 MB
  float* sq             = (float*)(Xb + (size_t)N * D);        // 16 KB
  unsigned int* hp2u    = (unsigned int*)(sq + N);             // 16 KB
  unsigned int* nm2u    = hp2u + N;                            // 16 KB
  unsigned int* counter = nm2u + N;                            // 4 B

  prep_kernel<<<N, 128, 0, stream>>>(X, Xb, sq, hp2u, nm2u, counter);
  gemm_fused<<<NBLK, 256, 0, stream>>>(Xb, sq, lab, hp2u, nm2u, counter, out);
}

// Round 7
// 117.402 us; speedup vs baseline: 1.2319x; 1.2319x over previous
//
#include <hip/hip_runtime.h>
#include <hip/hip_bf16.h>
#include <string.h>

#define N 4096
#define D 512
#define NB 32            // N/128 regions; triangle regions = NB*(NB+1)/2 = 528
#define NBLK (NB*(NB+1)/2)
#define MARGIN 0.5f
#define FINF __builtin_huge_valf()
#define UINF 0x7F800000u

// s_waitcnt immediates (gfx9 encoding): vmcnt [3:0]+[15:14], expcnt [6:4], lgkmcnt [11:8]
#define WAITCNT_VM0   0x0F70   // vmcnt(0), lgkm/exp unconstrained
#define WAITCNT_LGKM0 0xC07F   // lgkmcnt(0), vm/exp unconstrained

typedef __attribute__((ext_vector_type(8))) short bf16x8;   // 8 bf16 (4 VGPRs)
typedef __attribute__((ext_vector_type(4))) float f32x4;

__device__ inline float wave_sum(float v){
  #pragma unroll
  for (int off=32; off>0; off>>=1) v += __shfl_down(v, off, 64);
  return v;
}

// Pass 0: X (f32) -> bf16, row squared norms, init atomic arrays + ticket counter.
__global__ __launch_bounds__(128) void prep_kernel(const float* __restrict__ X,
    __hip_bfloat16* __restrict__ Xb, float* __restrict__ sq,
    unsigned int* __restrict__ hp2u, unsigned int* __restrict__ nm2u,
    unsigned int* __restrict__ counter){
  const int row = blockIdx.x;
  const int t = threadIdx.x;
  const float4 v = *(const float4*)(X + (size_t)row*D + t*4);
  ushort4 s;
  __hip_bfloat16 h;
  h = __float2bfloat16(v.x); memcpy(&s.x, &h, 2);
  h = __float2bfloat16(v.y); memcpy(&s.y, &h, 2);
  h = __float2bfloat16(v.z); memcpy(&s.z, &h, 2);
  h = __float2bfloat16(v.w); memcpy(&s.w, &h, 2);
  *(ushort4*)((unsigned short*)Xb + (size_t)row*D + t*4) = s;
  float ss = v.x*v.x + v.y*v.y + v.z*v.z + v.w*v.w;
  ss = wave_sum(ss);
  __shared__ float red[2];
  if ((t & 63) == 0) red[t >> 6] = ss;
  __syncthreads();
  if (t == 0){
    sq[row] = red[0] + red[1];
    hp2u[row] = 0u;                 // max-accumulator (d^2 domain, >= 0)
    nm2u[row] = UINF;               // +inf: min-accumulator
    if (row == 0) counter[0] = 0u;
  }
}

// Fused triangle GEMM + hardest-pos/neg reductions + last-block final reduce.
// Each of the 4 waves owns one 64x64 quadrant of the block's 128x128 region,
// staged into WAVE-PRIVATE LDS buffers -> the K-loop has ZERO __syncthreads;
// the only waits are the wave's own s_waitcnt vm/lgkm. 36 KB LDS/block keeps
// the whole 528-block grid co-resident (~16 independent waves/CU).
__global__ __launch_bounds__(256,2) void gemm_fused(const __hip_bfloat16* __restrict__ Xb,
    const float* __restrict__ sq, const int* __restrict__ lab,
    unsigned int* __restrict__ hp2u, unsigned int* __restrict__ nm2u,
    unsigned int* __restrict__ counter, float* __restrict__ out){
  __shared__ __align__(16) __hip_bfloat16 As[4][64*32];   // 16 KB: per-wave A tile
  __shared__ __align__(16) __hip_bfloat16 Bs[4][64*32];   // 16 KB: per-wave B tile
  __shared__ float sqi[128];
  __shared__ float sqj[128];
  __shared__ int labi_s[128];
  __shared__ int labj_s[128];
  __shared__ unsigned int hpl[128], nml[128];   // region-row combine
  __shared__ unsigned int hpc[128], nmc[128];   // region-col combine
  __shared__ unsigned int tick;

  // linear block -> region (bi, bj) with bi <= bj
  int rem = blockIdx.x, bi = 0;
  while (rem >= NB - bi){ rem -= NB - bi; bi++; }
  const int bj = bi + rem;
  const int row0 = bi * 128, col0 = bj * 128;

  const int tid = threadIdx.x;
  const int wave = tid >> 6, lane = tid & 63;
  const int trow0 = row0 + (wave >> 1) * 64;   // this wave's 64-row strip
  const int tcol0 = col0 + (wave & 1) * 64;    // this wave's 64-col strip

  if (tid < 128) {
    sqi[tid] = sq[row0 + tid]; sqj[tid] = sq[col0 + tid];
    labi_s[tid] = lab[row0 + tid]; labj_s[tid] = lab[col0 + tid];
    hpl[tid] = 0u; nml[tid] = UINF; hpc[tid] = 0u; nmc[tid] = UINF;
  }

  // Staging geometry (BK=32, rows are 64 B = 4 x 16B chunks):
  // LDS slot s of row r holds global chunk g = s ^ ((r>>1)&3)  -> bank-uniform reads.
  // Lane -> row = lane>>2 (within 16-row group), slot = lane&3  (dest = base+lane*16),
  // so the lane fetches g = (lane&3) ^ ((lane>>3)&3).
  const int srow = lane >> 2;
  const int sg   = (lane & 3) ^ ((lane >> 3) & 3);
  const __hip_bfloat16* Abase = Xb + (size_t)trow0 * D;
  const __hip_bfloat16* Bbase = Xb + (size_t)tcol0 * D;
  __hip_bfloat16* Aw = &As[wave][0];
  __hip_bfloat16* Bw = &Bs[wave][0];

  f32x4 acc[4][4];
  #pragma unroll
  for (int a=0;a<4;a++)
    #pragma unroll
    for (int b=0;b<4;b++)
      acc[a][b] = (f32x4){0.f,0.f,0.f,0.f};

  // Fragment geometry: A[m=lane&15][k=(lane>>4)*8+j]; chunk q with swizzle.
  const int fr = lane & 15, q = lane >> 4;
  const int fslot = q ^ ((fr >> 1) & 3);

  for (int it = 0; it < D/32; ++it){
    const int k0 = it * 32;
    __builtin_amdgcn_s_waitcnt(WAITCNT_LGKM0);   // prior ds_reads done before overwrite
    __asm__ volatile("" ::: "memory");
    #pragma unroll
    for (int c = 0; c < 4; ++c){
      const __hip_bfloat16* ga = Abase + (size_t)(c*16 + srow)*D + k0 + sg*8;
      const __hip_bfloat16* gb = Bbase + (size_t)(c*16 + srow)*D + k0 + sg*8;
      __builtin_amdgcn_global_load_lds((const __attribute__((address_space(1))) void*)ga,
          (__attribute__((address_space(3))) void*)(Aw + c*16*32), 16, 0, 0);
      __builtin_amdgcn_global_load_lds((const __attribute__((address_space(1))) void*)gb,
          (__attribute__((address_space(3))) void*)(Bw + c*16*32), 16, 0, 0);
    }
    __builtin_amdgcn_s_waitcnt(WAITCNT_VM0);     // own DMA complete -> LDS valid
    __asm__ volatile("" ::: "memory");
    bf16x8 af[4], bfr[4];
    #pragma unroll
    for (int a=0;a<4;a++){
      af[a]  = *(const bf16x8*)(Aw + (a*16 + fr)*32 + fslot*8);
      bfr[a] = *(const bf16x8*)(Bw + (a*16 + fr)*32 + fslot*8);
    }
    #pragma unroll
    for (int a=0;a<4;a++)
      #pragma unroll
      for (int b=0;b<4;b++)
        acc[a][b] = __builtin_amdgcn_mfma_f32_16x16x32_bf16(af[a], bfr[b], acc[a][b], 0, 0, 0);
  }

  __syncthreads();   // sqi/labi/combine-array init visible (first & only pre-epilogue barrier)

  // Epilogue. C/D layout: col=lane&15, row=(lane>>4)*4+v (m89-verified).
  // Local row within region = (wave>>1)*64 + a*16 + g4*4 + v; col = (wave&1)*64 + b*16 + colq.
  const int colq = lane & 15, g4 = lane >> 4, rowq = g4 * 4;
  const int rbase_l = (wave >> 1) * 64, cbase_l = (wave & 1) * 64;
  int   labi_r[16]; float sqi_r[16];
  #pragma unroll
  for (int a=0;a<4;a++)
    #pragma unroll
    for (int v=0;v<4;v++){
      const int iloc = rbase_l + a*16 + rowq + v;
      labi_r[a*4+v] = labi_s[iloc];
      sqi_r[a*4+v]  = sqi[iloc];
    }

  float pmax_r[16], nmin_r[16];
  #pragma unroll
  for (int k=0;k<16;k++){ pmax_r[k] = 0.f; nmin_r[k] = FINF; }
  float cpos[4], cmin[4];

  #pragma unroll
  for (int b=0;b<4;b++){
    const int jloc = cbase_l + b*16 + colq;
    const float sj = sqj[jloc];
    const int lj = labj_s[jloc];
    float cp = 0.f, cn = FINF;
    #pragma unroll
    for (int a=0;a<4;a++)
      #pragma unroll
      for (int v=0;v<4;v++){
        const int k = a*4+v;
        const float d2 = fmaf(acc[a][b][v], -2.0f, sqi_r[k] + sj);
        const bool same = (labi_r[k] == lj);         // covers diag (i==j)
        const float sp = same ? d2 : 0.0f;           // positive candidate
        const float sn = same ? FINF : d2;           // negative candidate
        pmax_r[k] = fmaxf(pmax_r[k], sp);
        nmin_r[k] = fminf(nmin_r[k], sn);
        cp = fmaxf(cp, sp);
        cn = fminf(cn, sn);
      }
    cpos[b] = cp; cmin[b] = cn;
  }

  // Row-direction: xor-reduce across the 16 lanes sharing a row -> LDS atomic.
  #pragma unroll
  for (int k=0;k<16;k++){
    float p = pmax_r[k], n = nmin_r[k];
    #pragma unroll
    for (int m=1;m<16;m<<=1){
      p = fmaxf(p, __shfl_xor(p, m, 64));
      n = fminf(n, __shfl_xor(n, m, 64));
    }
    if (colq == 0){
      const int il = rbase_l + (k>>2)*16 + rowq + (k&3);
      atomicMax(&hpl[il], __float_as_uint(p));                 // p >= 0
      atomicMin(&nml[il], __float_as_uint(fmaxf(n, 0.f)));     // clamp: monotone
    }
  }
  // Column-direction (symmetry): xor-reduce across the 4 lane-groups -> LDS atomic.
  #pragma unroll
  for (int b=0;b<4;b++){
    float p = cpos[b], n = cmin[b];
    p = fmaxf(p, __shfl_xor(p, 16, 64)); p = fmaxf(p, __shfl_xor(p, 32, 64));
    n = fminf(n, __shfl_xor(n, 16, 64)); n = fminf(n, __shfl_xor(n, 32, 64));
    if (g4 == 0){
      const int jl = cbase_l + b*16 + colq;
      atomicMax(&hpc[jl], __float_as_uint(p));
      atomicMin(&nmc[jl], __float_as_uint(fmaxf(n, 0.f)));
    }
  }

  __syncthreads();
  // One global flush: threads 0-127 do region rows, 128-255 region cols.
  if (tid < 128){
    atomicMax(hp2u + row0 + tid, hpl[tid]);
    atomicMin(nm2u + row0 + tid, nml[tid]);
  } else {
    const int t2 = tid - 128;
    atomicMax(hp2u + col0 + t2, hpc[t2]);
    atomicMin(nm2u + col0 + t2, nmc[t2]);
  }

  // Last-block final reduction (ticket).
  __threadfence();
  __syncthreads();
  if (tid == 0) tick = atomicAdd(counter, 1u);
  __syncthreads();
  if (tick == NBLK - 1){
    float s = 0.f;
    #pragma unroll
    for (int itr = 0; itr < 16; ++itr){
      const int i = tid + itr * 256;
      // non-destructive device-scope atomic reads (max(x,0)=x for our domains)
      const float hp2 = __uint_as_float(atomicMax(hp2u + i, 0u));
      const float nm2 = __uint_as_float(atomicMax(nm2u + i, 0u));
      s += sqrtf(hp2 + 1e-12f) + fmaxf(MARGIN - sqrtf(nm2 + 1e-12f), 0.f);
    }
    s = wave_sum(s);
    if ((tid & 63) == 0) sqi[tid >> 6] = s;   // reuse LDS as scratch
    __syncthreads();
    if (tid == 0) out[0] = (sqi[0] + sqi[1] + sqi[2] + sqi[3]) * (1.0f / (float)N);
  }
}

extern "C" void kernel_launch(void* const* d_in, const int* in_sizes, int n_in,
                              void* d_out, int out_size, void* d_ws, size_t ws_size,
                              hipStream_t stream) {
  (void)in_sizes; (void)n_in; (void)out_size; (void)ws_size;
  const float* X  = (const float*)d_in[0];
  const int* lab  = (const int*)d_in[1];
  float* out      = (float*)d_out;

  char* ws = (char*)d_ws;
  __hip_bfloat16* Xb    = (__hip_bfloat16*)ws;                 // 4 MB
  float* sq             = (float*)(Xb + (size_t)N * D);        // 16 KB
  unsigned int* hp2u    = (unsigned int*)(sq + N);             // 16 KB
  unsigned int* nm2u    = hp2u + N;                            // 16 KB
  unsigned int* counter = nm2u + N;                            // 4 B

  prep_kernel<<<N, 128, 0, stream>>>(X, Xb, sq, hp2u, nm2u, counter);
  gemm_fused<<<NBLK, 256, 0, stream>>>(Xb, sq, lab, hp2u, nm2u, counter, out);
}